// Round 4
// baseline (361.070 us; speedup 1.0000x reference)
//
#include <hip/hip_runtime.h>
#include <hip/hip_bf16.h>

typedef __attribute__((ext_vector_type(4))) float f32x4;
typedef __attribute__((ext_vector_type(8))) short s16x8;

#define X_ELEMS 25690112          // 32*64*112*112
#define X_F4    6422528           // X_ELEMS/4
#define NG_FULL 713614            // X_ELEMS/36 (rem 8)
#define NG      713615
#define HW 112
#define CHW (64*112*112)          // 802816
#define PSTR 2600                 // shorts per c-octet plane in conv LDS (324*8 + 8 pad)

// q = I * 2^(e-7), |I|<=256 -> exactly representable in bf16; low 16 fp32 bits are 0.
__device__ __forceinline__ unsigned short f32_to_bf16_exact(float q) {
    return (unsigned short)(__float_as_uint(q) >> 16);
}

__device__ __forceinline__ void scale_from_max(float m, float& scale, float& inv) {
    if (m > 0.f) {
        int e = (int)((__float_as_uint(m) >> 23) & 0xFF) - 127;  // exact floor(log2(m)) for normal m
        scale = __builtin_ldexpf(1.0f, e - 7);
        inv   = __builtin_ldexpf(1.0f, 7 - e);
    } else { scale = 0.f; inv = 0.f; }
}

// ---- Q1 (+fused QW): per-group scales for x; last block quantizes weight ----
__global__ __launch_bounds__(256) void q1_scales(const float* __restrict__ x,
                                                 float2* __restrict__ sc,
                                                 const float* __restrict__ w,
                                                 unsigned short* __restrict__ wt) {
    __shared__ float lmax[2304];
    int b = blockIdx.x, tid = threadIdx.x;
    if (b == 2788) {                              // weight block
        #pragma unroll
        for (int gi = 0; gi < 4; ++gi) {
            int g = gi * 256 + tid;               // 1024 groups of 36 (exact)
            const float4* p = (const float4*)w + g * 9;
            float vv[36]; float m = 0.f;
            #pragma unroll
            for (int i = 0; i < 9; ++i) {
                float4 v = p[i];
                vv[i*4+0]=v.x; vv[i*4+1]=v.y; vv[i*4+2]=v.z; vv[i*4+3]=v.w;
                m = fmaxf(m, fmaxf(fmaxf(fabsf(v.x), fabsf(v.y)), fmaxf(fabsf(v.z), fabsf(v.w))));
            }
            float s, inv; scale_from_max(m, s, inv);
            #pragma unroll
            for (int j = 0; j < 36; ++j) {
                int flat = g * 36 + j;
                int k = flat / 576, rem = flat % 576;
                int c = rem / 9, pp = rem % 9;
                float q = rintf(vv[j] * inv) * s;
                wt[pp * 4096 + k * 64 + c] = f32_to_bf16_exact(q);
            }
        }
        return;
    }
    long base4 = (long)b * 2304;
    #pragma unroll
    for (int it = 0; it < 9; ++it) {
        int i = it * 256 + tid;
        long g4 = base4 + i;
        float m = 0.f;
        if (g4 < X_F4) {
            float4 v = ((const float4*)x)[g4];
            m = fmaxf(fmaxf(fabsf(v.x), fabsf(v.y)), fmaxf(fabsf(v.z), fabsf(v.w)));
        }
        lmax[i] = m;
    }
    __syncthreads();
    int g = b * 256 + tid;
    if (g < NG) {
        float m = 0.f;
        int o = tid * 9;                      // stride-9 over 32 banks: 2-way, free
        #pragma unroll
        for (int j = 0; j < 9; ++j) m = fmaxf(m, lmax[o + j]);
        float s, inv; scale_from_max(m, s, inv);
        sc[g] = make_float2(s, inv);
    }
}

// ---- Q2: quantize x, NCHW -> NHWC bf16, no LDS. Thread owns (w, 32 c's). ----
__global__ __launch_bounds__(256) void q2_quant(const float* __restrict__ x,
                                               const float2* __restrict__ sc,
                                               unsigned short* __restrict__ xt) {
    int n = blockIdx.y, h = blockIdx.x;
    int tid = threadIdx.x;
    int cg = tid >> 7;                 // 0/1 -> c 0-31 / 32-63
    int wv = tid & 127;
    if (wv >= HW) return;
    int base = n * CHW + h * HW + wv;
    int ob = ((n * HW + h) * HW + wv) * 64 + cg * 32;
    #pragma unroll
    for (int jo = 0; jo < 4; ++jo) {
        union { unsigned short u[8]; uint4 d; } pk;
        #pragma unroll
        for (int j = 0; j < 8; ++j) {
            int c = cg * 32 + jo * 8 + j;
            unsigned off = (unsigned)(base + c * 12544);
            float v = x[off];
            float2 s = sc[off / 36u];
            pk.u[j] = f32_to_bf16_exact(rintf(v * s.y) * s.x);
        }
        *(uint4*)(xt + ob + jo * 8) = pk.d;
    }
}

// ---- conv: tile 16h x 16w x 64k, grid 1568, 3 blocks/CU.
// 4 waves = 2 k-halves x 2 m-halves; B double-buffered over p (32 VGPR live);
// LDS halo oct-major 18x18x64 (41.6 KB), conflict-free b128 A-reads;
// output segments 64B-sector aligned (no RMW). ----
__global__ __launch_bounds__(256, 3) void conv_mfma(const unsigned short* __restrict__ xt,
                                                    const unsigned short* __restrict__ wt,
                                                    const float* __restrict__ bias,
                                                    float* __restrict__ out) {
    __shared__ unsigned short xs[8 * PSTR];
    const int tid = threadIdx.x;
    const int wave = tid >> 6, lane = tid & 63;
    const int wl = lane & 15, quad = lane >> 4;
    const int kg = wave & 1, mg = wave >> 1;
    const int b = blockIdx.x;
    const int n = b / 49, rem = b % 49;
    const int h0 = (rem / 7) * 16, w0 = (rem % 7) * 16;

    // prefetch B[p=0] (L2-hot after q1's weight block)
    s16x8 Bcur[2][2], Bnxt[2][2];
    #pragma unroll
    for (int cs = 0; cs < 2; ++cs)
        #pragma unroll
        for (int j = 0; j < 2; ++j)
            Bcur[cs][j] = *(const s16x8*)(wt + (kg * 32 + j * 16 + wl) * 64 + cs * 32 + quad * 8);

    // stage 18x18x64 halo, oct-major: xs[oct*PSTR + pixel*8]
    #pragma unroll
    for (int it = 0; it < 11; ++it) {
        int q = it * 256 + tid;
        if (q < 2592) {
            int pixel = q >> 3, oct = q & 7;
            int r = pixel / 18, col = pixel % 18;
            int hh = h0 + r - 1, ww = w0 + col - 1;
            uint4 v = {0u, 0u, 0u, 0u};
            if (hh >= 0 && hh < HW && ww >= 0 && ww < HW)
                v = *(const uint4*)(xt + (((n * HW + hh) * HW + ww) << 6) + oct * 8);
            *(uint4*)&xs[oct * PSTR + pixel * 8] = v;
        }
    }

    float bv[2];
    #pragma unroll
    for (int j = 0; j < 2; ++j) bv[j] = bias[kg * 32 + j * 16 + wl];

    int pb[8];
    #pragma unroll
    for (int mti = 0; mti < 8; ++mti)
        pb[mti] = ((mg * 8 + mti) * 18 + wl) * 8;   // halo pixel base (row = mg*8+mti, col = wl)

    f32x4 acc[8][2];
    f32x4 zero = {0.f, 0.f, 0.f, 0.f};
    #pragma unroll
    for (int mti = 0; mti < 8; ++mti) { acc[mti][0] = zero; acc[mti][1] = zero; }

    __syncthreads();

    #pragma unroll
    for (int p = 0; p < 9; ++p) {
        if (p < 8) {                                // prefetch next B while computing
            #pragma unroll
            for (int cs = 0; cs < 2; ++cs)
                #pragma unroll
                for (int j = 0; j < 2; ++j)
                    Bnxt[cs][j] = *(const s16x8*)(wt + (p + 1) * 4096 +
                                    (kg * 32 + j * 16 + wl) * 64 + cs * 32 + quad * 8);
        }
        const int dpix = ((p / 3) * 18 + (p % 3)) * 8;
        #pragma unroll
        for (int cs = 0; cs < 2; ++cs) {
            const int cbase = (cs * 4 + quad) * PSTR + dpix;
            #pragma unroll
            for (int mti = 0; mti < 8; ++mti) {
                s16x8 A = *(const s16x8*)&xs[cbase + pb[mti]];
                acc[mti][0] = __builtin_amdgcn_mfma_f32_16x16x32_bf16(A, Bcur[cs][0], acc[mti][0], 0, 0, 0);
                acc[mti][1] = __builtin_amdgcn_mfma_f32_16x16x32_bf16(A, Bcur[cs][1], acc[mti][1], 0, 0, 0);
            }
        }
        #pragma unroll
        for (int cs = 0; cs < 2; ++cs)
            #pragma unroll
            for (int j = 0; j < 2; ++j)
                Bcur[cs][j] = Bnxt[cs][j];
    }

    // epilogue: k = kg*32+j*16+wl, h = h0+mg*8+mti, w = w0+quad*4 -> 64B-aligned sectors
    int obase = n * CHW + h0 * HW + w0 + quad * 4;
    #pragma unroll
    for (int mti = 0; mti < 8; ++mti) {
        #pragma unroll
        for (int j = 0; j < 2; ++j) {
            f32x4 v = acc[mti][j];
            v.x += bv[j]; v.y += bv[j]; v.z += bv[j]; v.w += bv[j];
            *(f32x4*)(out + obase + (kg * 32 + j * 16 + wl) * 12544 + (mg * 8 + mti) * HW) = v;
        }
    }
}

extern "C" void kernel_launch(void* const* d_in, const int* in_sizes, int n_in,
                              void* d_out, int out_size, void* d_ws, size_t ws_size,
                              hipStream_t stream) {
    const float* x    = (const float*)d_in[0];
    const float* w    = (const float*)d_in[1];
    const float* bias = (const float*)d_in[2];
    float* out = (float*)d_out;
    char* ws = (char*)d_ws;
    unsigned short* xt = (unsigned short*)ws;                       // 51,380,224 B (NHWC bf16)
    unsigned short* wt = (unsigned short*)(ws + 51380224);          //     73,728 B
    float2*         sc = (float2*)(ws + 51380224 + 73728);          //  5,708,920 B

    hipLaunchKernelGGL(q1_scales, dim3(2789),    dim3(256), 0, stream, x, sc, w, wt);
    hipLaunchKernelGGL(q2_quant,  dim3(112, 32), dim3(256), 0, stream, x, sc, xt);
    hipLaunchKernelGGL(conv_mfma, dim3(1568),    dim3(256), 0, stream, xt, wt, bias, out);
}